// Round 2
// baseline (219.930 us; speedup 1.0000x reference)
//
#include <hip/hip_runtime.h>

#define NREPS   16
#define NELEMS  128
#define DD      32
#define MATSZ   (DD * DD)        // 1024 floats per 32x32 block
#define EMB     (NREPS * MATSZ)  // 16384

// One wave = one (batch, rep) 32x32 matmul out = A @ (M / (||M||_F + 1e-6)).
// Lane tile: 4 rows x 4 cols (16 acc). A rows and M rows are loaded straight
// from global with immediate offsets; same-address lanes are HW-merged and
// everything after first touch is L1/L2-resident. The Frobenius norm of M is
// accumulated on the fly (each lane covers cols j0..j0+3 over all 32 rows;
// the 8 column-groups are combined with 3 shuffles), so no separate pass.
__global__ __launch_bounds__(256) void trans_fused_kernel(
    const float* __restrict__ emb,     // [B][16384]
    const int*   __restrict__ syms,    // [B]
    const float* __restrict__ reps,    // [16][128][32][32]
    const int*   __restrict__ trans,   // [64]
    float*       __restrict__ out)     // [B][16384]
{
    const int bid = blockIdx.x;            // 0 .. B*4-1
    const int b   = bid >> 2;
    const int w   = threadIdx.x >> 6;      // wave 0..3
    const int l   = threadIdx.x & 63;
    const int r   = ((bid & 3) << 2) | w;  // rep 0..15
    const int i0  = (l >> 3) << 2;         // row base {0,4,...,28}
    const int j0  = (l & 7) << 2;          // col base {0,4,...,28}

    const int esym = trans[syms[b]];       // group element for this batch
    const float* A = emb  + (size_t)b * EMB + (size_t)r * MATSZ + i0 * DD;
    const float* M = reps + ((size_t)r * NELEMS + esym) * MATSZ + j0;

    float acc[4][4];
    #pragma unroll
    for (int m = 0; m < 4; ++m)
        #pragma unroll
        for (int j = 0; j < 4; ++j) acc[m][j] = 0.0f;

    float ss = 0.0f;                       // sum of squares of M cols j0..j0+3

    #pragma unroll
    for (int kb = 0; kb < 8; ++kb) {       // contraction in chunks of 4
        float4 a[4];
        #pragma unroll
        for (int m = 0; m < 4; ++m)
            a[m] = *reinterpret_cast<const float4*>(A + m * DD + kb * 4);

        float4 mv[4];
        #pragma unroll
        for (int kk = 0; kk < 4; ++kk)
            mv[kk] = *reinterpret_cast<const float4*>(M + (kb * 4 + kk) * DD);

        #pragma unroll
        for (int kk = 0; kk < 4; ++kk) {
            ss += mv[kk].x * mv[kk].x + mv[kk].y * mv[kk].y
                + mv[kk].z * mv[kk].z + mv[kk].w * mv[kk].w;
            #pragma unroll
            for (int m = 0; m < 4; ++m) {
                const float av = (&a[m].x)[kk];   // kk compile-time (unrolled)
                acc[m][0] += av * mv[kk].x;
                acc[m][1] += av * mv[kk].y;
                acc[m][2] += av * mv[kk].z;
                acc[m][3] += av * mv[kk].w;
            }
        }
    }

    // Combine the 8 column-group partials (lanes differing in low 3 bits).
    ss += __shfl_xor(ss, 1, 64);
    ss += __shfl_xor(ss, 2, 64);
    ss += __shfl_xor(ss, 4, 64);
    const float scale = 1.0f / (sqrtf(ss) + 1e-6f);

    float* Ob = out + (size_t)b * EMB + (size_t)r * MATSZ + i0 * DD + j0;
    #pragma unroll
    for (int m = 0; m < 4; ++m) {
        float4 o = make_float4(acc[m][0] * scale, acc[m][1] * scale,
                               acc[m][2] * scale, acc[m][3] * scale);
        *reinterpret_cast<float4*>(Ob + m * DD) = o;
    }
}

extern "C" void kernel_launch(void* const* d_in, const int* in_sizes, int n_in,
                              void* d_out, int out_size, void* d_ws, size_t ws_size,
                              hipStream_t stream) {
    const float* emb   = (const float*)d_in[0];
    const int*   syms  = (const int*)d_in[1];
    const float* reps  = (const float*)d_in[2];
    const int*   trans = (const int*)d_in[3];
    float* outp = (float*)d_out;

    const int B = in_sizes[1];             // batch count (4096)

    hipLaunchKernelGGL(trans_fused_kernel, dim3(B * 4), dim3(256), 0, stream,
                       emb, syms, reps, trans, outp);
}

// Round 3
// 141.113 us; speedup vs baseline: 1.5585x; 1.5585x over previous
//
#include <hip/hip_runtime.h>

#define NREPS   16
#define NELEMS  128
#define DD      32
#define MATSZ   (DD * DD)        // 1024 floats per 32x32 block
#define EMB     (NREPS * MATSZ)  // 16384

// One wave = one (batch, rep) 32x32 matmul out = A @ (M / (||M||_F + 1e-6)).
// Each wave stages its own A (4 KiB) into LDS with fully-coalesced 1KiB
// global_load_dwordx4 (this is the transpose medium: coalesced in, row-tiled
// out). LDS layout is XOR-swizzled (slot = k4 ^ ((row>>2)&7)) so the 8 row
// groups of a read instruction hit 8 distinct bank quads -> conflict-free.
// M rows are read straight from global: <=1024 distinct matrices (4 MB) are
// L2-resident; each wave instruction touches one contiguous 128B row.
// The Frobenius norm is accumulated on the fly (lane covers cols j0..j0+3
// over all 32 rows; 3 shuffles combine the 8 column groups) -> single kernel.
__global__ __launch_bounds__(256) void trans_fused_kernel(
    const float* __restrict__ emb,     // [B][16384]
    const int*   __restrict__ syms,    // [B]
    const float* __restrict__ reps,    // [16][128][32][32]
    const int*   __restrict__ trans,   // [64]
    float*       __restrict__ out)     // [B][16384]
{
    __shared__ float lA[4 * MATSZ];        // 16 KiB: one 32x32 tile per wave
    const int bid = blockIdx.x;            // 0 .. B*4-1
    const int b   = bid >> 2;
    const int w   = threadIdx.x >> 6;      // wave 0..3
    const int l   = threadIdx.x & 63;
    const int r   = ((bid & 3) << 2) | w;  // rep 0..15

    const float* Aw = emb + (size_t)b * EMB + (size_t)r * MATSZ;
    float4* lw = reinterpret_cast<float4*>(lA + w * MATSZ);

    // ---- stage this wave's A tile: 4 x 1KiB coalesced loads, swizzled ----
    #pragma unroll
    for (int it = 0; it < 4; ++it) {
        const int f4 = it * 64 + l;        // float4 index 0..255
        float4 v = reinterpret_cast<const float4*>(Aw)[f4];
        const int i  = f4 >> 3;            // row 0..31
        const int k4 = f4 & 7;             // col block 0..7
        const int s  = (i >> 2) & 7;
        lw[i * 8 + (k4 ^ s)] = v;
    }
    __syncthreads();

    const int i0 = (l >> 3) << 2;          // row base {0,4,...,28}
    const int j0 = (l & 7) << 2;           // col base {0,4,...,28}
    const int sw = (l >> 3) & 7;           // swizzle term (const over m=0..3)

    const int esym = trans[syms[b]];       // group element for this batch
    const float* M = reps + ((size_t)r * NELEMS + esym) * MATSZ + j0;

    float acc[4][4];
    #pragma unroll
    for (int m = 0; m < 4; ++m)
        #pragma unroll
        for (int j = 0; j < 4; ++j) acc[m][j] = 0.0f;

    float ss = 0.0f;                       // sum of squares of M cols j0..j0+3

    #pragma unroll
    for (int kb = 0; kb < 8; ++kb) {       // contraction in chunks of 4
        float4 a[4];
        #pragma unroll
        for (int m = 0; m < 4; ++m)
            a[m] = lw[(i0 + m) * 8 + (kb ^ sw)];

        float4 mv[4];
        #pragma unroll
        for (int kk = 0; kk < 4; ++kk)
            mv[kk] = *reinterpret_cast<const float4*>(M + (kb * 4 + kk) * DD);

        #pragma unroll
        for (int kk = 0; kk < 4; ++kk) {
            ss += mv[kk].x * mv[kk].x + mv[kk].y * mv[kk].y
                + mv[kk].z * mv[kk].z + mv[kk].w * mv[kk].w;
            #pragma unroll
            for (int m = 0; m < 4; ++m) {
                const float av = (&a[m].x)[kk];   // kk compile-time (unrolled)
                acc[m][0] += av * mv[kk].x;
                acc[m][1] += av * mv[kk].y;
                acc[m][2] += av * mv[kk].z;
                acc[m][3] += av * mv[kk].w;
            }
        }
    }

    // Combine the 8 column-group partials (lanes differing in low 3 bits).
    ss += __shfl_xor(ss, 1, 64);
    ss += __shfl_xor(ss, 2, 64);
    ss += __shfl_xor(ss, 4, 64);
    const float scale = 1.0f / (sqrtf(ss) + 1e-6f);

    float* Ob = out + (size_t)b * EMB + (size_t)r * MATSZ + i0 * DD + j0;
    #pragma unroll
    for (int m = 0; m < 4; ++m) {
        float4 o = make_float4(acc[m][0] * scale, acc[m][1] * scale,
                               acc[m][2] * scale, acc[m][3] * scale);
        *reinterpret_cast<float4*>(Ob + m * DD) = o;
    }
}

extern "C" void kernel_launch(void* const* d_in, const int* in_sizes, int n_in,
                              void* d_out, int out_size, void* d_ws, size_t ws_size,
                              hipStream_t stream) {
    const float* emb   = (const float*)d_in[0];
    const int*   syms  = (const int*)d_in[1];
    const float* reps  = (const float*)d_in[2];
    const int*   trans = (const int*)d_in[3];
    float* outp = (float*)d_out;

    const int B = in_sizes[1];             // batch count (4096)

    hipLaunchKernelGGL(trans_fused_kernel, dim3(B * 4), dim3(256), 0, stream,
                       emb, syms, reps, trans, outp);
}

// Round 4
// 124.938 us; speedup vs baseline: 1.7603x; 1.1295x over previous
//
#include <hip/hip_runtime.h>

#define NREPS   16
#define NELEMS  128
#define DD      32
#define MATSZ   (DD * DD)        // 1024 floats per 32x32 block
#define EMB     (NREPS * MATSZ)  // 16384

// One wave = one (batch, rep) 32x32 matmul out = A @ (M / (||M||_F + 1e-6)).
// BOTH operands are staged into LDS with fully-coalesced 1KiB loads per wave:
//   A: XOR-swizzled (slot = k4 ^ ((row>>2)&7)) so the 8 row-groups of a
//      strided read hit 8 distinct bank quads -> conflict-free.
//   M: plain layout; reads are at a wave-uniform row k, so the 8 distinct j0
//      segments cover 8 distinct bank quads and the 8-lane address sharing is
//      a free same-address broadcast. One base VGPR + imm offsets.
// No __syncthreads(): each wave reads only the LDS it wrote itself, so the
// compiler's lgkmcnt ordering suffices and waves are fully independent.
// Frobenius norm is accumulated on the fly from the staged M values.
__global__ __launch_bounds__(256) void trans_fused_kernel(
    const float* __restrict__ emb,     // [B][16384]
    const int*   __restrict__ syms,    // [B]
    const float* __restrict__ reps,    // [16][128][32][32]
    const int*   __restrict__ trans,   // [64]
    float*       __restrict__ out)     // [B][16384]
{
    __shared__ float lA[4 * MATSZ];        // 16 KiB: A tile per wave (swizzled)
    __shared__ float lM[4 * MATSZ];        // 16 KiB: M tile per wave (linear)
    const int bid = blockIdx.x;            // 0 .. B*4-1
    const int b   = bid >> 2;
    const int w   = threadIdx.x >> 6;      // wave 0..3
    const int l   = threadIdx.x & 63;
    const int r   = ((bid & 3) << 2) | w;  // rep 0..15

    const int esym = trans[syms[b]];       // group element for this batch

    const float4* Ag = reinterpret_cast<const float4*>(
        emb + (size_t)b * EMB + (size_t)r * MATSZ);
    const float4* Mg = reinterpret_cast<const float4*>(
        reps + ((size_t)r * NELEMS + esym) * MATSZ);
    float4* lwA = reinterpret_cast<float4*>(lA + w * MATSZ);
    float4* lwM = reinterpret_cast<float4*>(lM + w * MATSZ);

    // ---- stage A (swizzled) and M (linear): 4+4 coalesced 1KiB loads ----
    #pragma unroll
    for (int it = 0; it < 4; ++it) {
        const int f4 = it * 64 + l;        // float4 index 0..255
        const int i  = f4 >> 3;            // row 0..31
        const int k4 = f4 & 7;             // col block 0..7
        lwA[i * 8 + (k4 ^ ((i >> 2) & 7))] = Ag[f4];
        lwM[f4] = Mg[f4];
    }
    // (no barrier: wave-private LDS regions)

    const int i0 = (l >> 3) << 2;          // row base {0,4,...,28}
    const int j0 = (l & 7);                // col float4-index 0..7
    const int sw = (l >> 3) & 7;           // A swizzle term

    float acc[4][4];
    #pragma unroll
    for (int m = 0; m < 4; ++m)
        #pragma unroll
        for (int j = 0; j < 4; ++j) acc[m][j] = 0.0f;

    float ss = 0.0f;                       // sum of squares of M cols j0*4..+3

    #pragma unroll
    for (int kb = 0; kb < 8; ++kb) {       // contraction in chunks of 4
        float4 a[4];
        #pragma unroll
        for (int m = 0; m < 4; ++m)
            a[m] = lwA[(i0 + m) * 8 + (kb ^ sw)];

        float4 mv[4];
        #pragma unroll
        for (int kk = 0; kk < 4; ++kk)
            mv[kk] = lwM[(kb * 4 + kk) * 8 + j0];

        #pragma unroll
        for (int kk = 0; kk < 4; ++kk) {
            ss += mv[kk].x * mv[kk].x + mv[kk].y * mv[kk].y
                + mv[kk].z * mv[kk].z + mv[kk].w * mv[kk].w;
            #pragma unroll
            for (int m = 0; m < 4; ++m) {
                const float av = (&a[m].x)[kk];   // kk compile-time (unrolled)
                acc[m][0] += av * mv[kk].x;
                acc[m][1] += av * mv[kk].y;
                acc[m][2] += av * mv[kk].z;
                acc[m][3] += av * mv[kk].w;
            }
        }
    }

    // Combine the 8 column-group partials (lanes differing in low 3 bits).
    ss += __shfl_xor(ss, 1, 64);
    ss += __shfl_xor(ss, 2, 64);
    ss += __shfl_xor(ss, 4, 64);
    const float scale = 1.0f / (sqrtf(ss) + 1e-6f);

    float* Ob = out + (size_t)b * EMB + (size_t)r * MATSZ + i0 * DD + j0 * 4;
    #pragma unroll
    for (int m = 0; m < 4; ++m) {
        float4 o = make_float4(acc[m][0] * scale, acc[m][1] * scale,
                               acc[m][2] * scale, acc[m][3] * scale);
        *reinterpret_cast<float4*>(Ob + m * DD) = o;
    }
}

extern "C" void kernel_launch(void* const* d_in, const int* in_sizes, int n_in,
                              void* d_out, int out_size, void* d_ws, size_t ws_size,
                              hipStream_t stream) {
    const float* emb   = (const float*)d_in[0];
    const int*   syms  = (const int*)d_in[1];
    const float* reps  = (const float*)d_in[2];
    const int*   trans = (const int*)d_in[3];
    float* outp = (float*)d_out;

    const int B = in_sizes[1];             // batch count (4096)

    hipLaunchKernelGGL(trans_fused_kernel, dim3(B * 4), dim3(256), 0, stream,
                       emb, syms, reps, trans, outp);
}

// Round 5
// 121.489 us; speedup vs baseline: 1.8103x; 1.0284x over previous
//
#include <hip/hip_runtime.h>

#define NREPS   16
#define NELEMS  128
#define DD      32
#define MATSZ   (DD * DD)        // 1024 floats per 32x32 block
#define EMB     (NREPS * MATSZ)  // 16384

// One block = one batch (256 thr, 4 waves). Wave w processes reps w*4+p,
// p = 0..3, software-pipelined: while pair p is computed from LDS, pair
// p+1's 8 global loads (A 4KB + M 4KB, fully coalesced 1KiB/instr) are in
// flight into registers; the ds_write of p+1 happens after compute(p)
// (same-wave DS ops are ordered, so slot reuse is safe). This hides the
// ~900cy staging latency under ~1300cy of FMA instead of serializing them.
// A is XOR-swizzled in LDS (slot = k4 ^ ((row>>2)&7)) -> strided row reads
// conflict-free; M is linear (row reads are 8-lane broadcasts, free).
// Frobenius ss is computed at staging time from the in-register M values
// (16 FMA/lane over the full matrix) + 6 shfl_xor -- removing the 128-FMA
// ss chain from the inner loop.
__global__ __launch_bounds__(256) void trans_fused_kernel(
    const float* __restrict__ emb,     // [B][16384]
    const int*   __restrict__ syms,    // [B]
    const float* __restrict__ reps,    // [16][128][32][32]
    const int*   __restrict__ trans,   // [64]
    float*       __restrict__ out)     // [B][16384]
{
    __shared__ float lA[4 * MATSZ];        // 16 KiB: A slot per wave (swizzled)
    __shared__ float lM[4 * MATSZ];        // 16 KiB: M slot per wave (linear)
    const int b = blockIdx.x;
    const int w = threadIdx.x >> 6;        // wave 0..3
    const int l = threadIdx.x & 63;

    const int esym = trans[syms[b]];       // group element for this batch

    float4* lwA = reinterpret_cast<float4*>(lA + w * MATSZ);
    float4* lwM = reinterpret_cast<float4*>(lM + w * MATSZ);

    const int i0 = (l >> 3) << 2;          // row base {0,4,...,28}
    const int j0 = l & 7;                  // col float4-index 0..7
    const int sw = (l >> 3) & 7;           // A swizzle term

    float4 ra[4], rm[4];                   // register staging (next pair)

    // ---- prologue: load + stage pair 0 ----
    {
        const float4* Ag = reinterpret_cast<const float4*>(
            emb + (size_t)b * EMB + (size_t)(w * 4) * MATSZ);
        const float4* Mg = reinterpret_cast<const float4*>(
            reps + ((size_t)(w * 4) * NELEMS + esym) * MATSZ);
        #pragma unroll
        for (int it = 0; it < 4; ++it) { ra[it] = Ag[it * 64 + l]; rm[it] = Mg[it * 64 + l]; }
    }
    float ss_cur = 0.0f, ss_nxt = 0.0f;
    #pragma unroll
    for (int it = 0; it < 4; ++it) {
        const int f4 = it * 64 + l;
        const int i = f4 >> 3, k4 = f4 & 7;
        lwA[i * 8 + (k4 ^ ((i >> 2) & 7))] = ra[it];
        lwM[f4] = rm[it];
        ss_cur += rm[it].x * rm[it].x + rm[it].y * rm[it].y
                + rm[it].z * rm[it].z + rm[it].w * rm[it].w;
    }

    #pragma unroll
    for (int p = 0; p < 4; ++p) {
        const int r = w * 4 + p;

        // ---- issue next pair's global loads (in flight during compute) ----
        if (p < 3) {
            const float4* Ag = reinterpret_cast<const float4*>(
                emb + (size_t)b * EMB + (size_t)(r + 1) * MATSZ);
            const float4* Mg = reinterpret_cast<const float4*>(
                reps + ((size_t)(r + 1) * NELEMS + esym) * MATSZ);
            #pragma unroll
            for (int it = 0; it < 4; ++it) { ra[it] = Ag[it * 64 + l]; rm[it] = Mg[it * 64 + l]; }
        }

        // ---- compute pair p from LDS ----
        float acc[4][4];
        #pragma unroll
        for (int m = 0; m < 4; ++m)
            #pragma unroll
            for (int j = 0; j < 4; ++j) acc[m][j] = 0.0f;

        #pragma unroll
        for (int kb = 0; kb < 8; ++kb) {
            float4 a[4];
            #pragma unroll
            for (int m = 0; m < 4; ++m)
                a[m] = lwA[(i0 + m) * 8 + (kb ^ sw)];
            float4 mv[4];
            #pragma unroll
            for (int kk = 0; kk < 4; ++kk)
                mv[kk] = lwM[(kb * 4 + kk) * 8 + j0];
            #pragma unroll
            for (int kk = 0; kk < 4; ++kk)
                #pragma unroll
                for (int m = 0; m < 4; ++m) {
                    const float av = (&a[m].x)[kk];   // kk compile-time
                    acc[m][0] += av * mv[kk].x;
                    acc[m][1] += av * mv[kk].y;
                    acc[m][2] += av * mv[kk].z;
                    acc[m][3] += av * mv[kk].w;
                }
        }

        // ---- stage next pair into LDS (after compute's reads; DS in-order) ----
        if (p < 3) {
            ss_nxt = 0.0f;
            #pragma unroll
            for (int it = 0; it < 4; ++it) {
                const int f4 = it * 64 + l;
                const int i = f4 >> 3, k4 = f4 & 7;
                lwA[i * 8 + (k4 ^ ((i >> 2) & 7))] = ra[it];
                lwM[f4] = rm[it];
                ss_nxt += rm[it].x * rm[it].x + rm[it].y * rm[it].y
                        + rm[it].z * rm[it].z + rm[it].w * rm[it].w;
            }
        }

        // ---- Frobenius scale for pair p (full-wave reduction) ----
        float ss = ss_cur;
        ss += __shfl_xor(ss, 1, 64);
        ss += __shfl_xor(ss, 2, 64);
        ss += __shfl_xor(ss, 4, 64);
        ss += __shfl_xor(ss, 8, 64);
        ss += __shfl_xor(ss, 16, 64);
        ss += __shfl_xor(ss, 32, 64);
        const float scale = 1.0f / (sqrtf(ss) + 1e-6f);

        float* Ob = out + (size_t)b * EMB + (size_t)r * MATSZ + i0 * DD + j0 * 4;
        #pragma unroll
        for (int m = 0; m < 4; ++m) {
            float4 o = make_float4(acc[m][0] * scale, acc[m][1] * scale,
                                   acc[m][2] * scale, acc[m][3] * scale);
            *reinterpret_cast<float4*>(Ob + m * DD) = o;
        }
        ss_cur = ss_nxt;
    }
}

extern "C" void kernel_launch(void* const* d_in, const int* in_sizes, int n_in,
                              void* d_out, int out_size, void* d_ws, size_t ws_size,
                              hipStream_t stream) {
    const float* emb   = (const float*)d_in[0];
    const int*   syms  = (const int*)d_in[1];
    const float* reps  = (const float*)d_in[2];
    const int*   trans = (const int*)d_in[3];
    float* outp = (float*)d_out;

    const int B = in_sizes[1];             // batch count (4096)

    hipLaunchKernelGGL(trans_fused_kernel, dim3(B), dim3(256), 0, stream,
                       emb, syms, reps, trans, outp);
}

// Round 6
// 107.349 us; speedup vs baseline: 2.0487x; 1.1317x over previous
//
#include <hip/hip_runtime.h>
#include <hip/hip_bf16.h>

#define NREPS   16
#define NELEMS  128
#define DD      32
#define MATSZ   (DD * DD)        // 1024 elements per 32x32 block
#define EMB     (NREPS * MATSZ)  // 16384

typedef __attribute__((ext_vector_type(8))) short bf16x8;  // 8 bf16 = 4 VGPR
typedef __attribute__((ext_vector_type(4))) float f32x4;   // MFMA C/D frag

static __device__ __forceinline__ short f2bf(float f) {
    __hip_bfloat16 h = __float2bfloat16(f);   // RTN; compiler emits v_cvt_pk
    return *reinterpret_cast<short*>(&h);
}

// ---- Prep: Mt[mat][col][k] = bf16( reps[mat][k][col] / (||.||_F + 1e-6) ) ----
// One block per (r,e) matrix. Coalesced 4KB read, padded-LDS transpose,
// coalesced 2KB bf16 write. Norm + transpose leave the hot path entirely.
__global__ __launch_bounds__(256) void prep_kernel(
    const float* __restrict__ reps, ushort* __restrict__ Mt)
{
    __shared__ float lM[DD * 33];          // +1 pad: transpose reads 2-way max
    __shared__ float red[4];
    const int mat = blockIdx.x;            // r*128 + e
    const int t   = threadIdx.x;           // 0..255

    float4 v = reinterpret_cast<const float4*>(reps + (size_t)mat * MATSZ)[t];
    const int i  = t >> 3;                 // row
    const int c0 = (t & 7) << 2;           // col base
    lM[i * 33 + c0 + 0] = v.x;
    lM[i * 33 + c0 + 1] = v.y;
    lM[i * 33 + c0 + 2] = v.z;
    lM[i * 33 + c0 + 3] = v.w;

    float s = v.x * v.x + v.y * v.y + v.z * v.z + v.w * v.w;
    #pragma unroll
    for (int off = 32; off; off >>= 1) s += __shfl_xor(s, off, 64);
    if ((t & 63) == 0) red[t >> 6] = s;
    __syncthreads();
    const float scale = 1.0f / (sqrtf(red[0] + red[1] + red[2] + red[3]) + 1e-6f);

    // thread t writes transposed elements q = t*4..t*4+3 (q = col*32 + k)
    const int col = t >> 3;
    const int k0  = (t & 7) << 2;
    ushort4 o;
    o.x = (ushort)f2bf(lM[(k0 + 0) * 33 + col] * scale);
    o.y = (ushort)f2bf(lM[(k0 + 1) * 33 + col] * scale);
    o.z = (ushort)f2bf(lM[(k0 + 2) * 33 + col] * scale);
    o.w = (ushort)f2bf(lM[(k0 + 3) * 33 + col] * scale);
    reinterpret_cast<ushort4*>(Mt + (size_t)mat * MATSZ)[t] = o;
}

// ---- Main: one wave = one (b,r); out = A @ Mn via 4x mfma_f32_16x16x32_bf16.
// A-frag: lane holds A[ti*16 + (l&15)][(l>>4)*8 .. +7] -> two dwordx4 straight
// from global (4KB/matrix read exactly once, no LDS, no broadcast).
// B-frag: lane holds Mn[k][tj*16 + (l&15)] = Mt row-major -> one dwordx4 from
// the pre-transposed table (L2-resident, 2KB/matrix).
// C-frag (m89-verified): row=(l>>4)*4+m, col=l&15.
__global__ __launch_bounds__(256) void trans_mfma_kernel(
    const float*  __restrict__ emb,    // [B][16384] fp32
    const int*    __restrict__ syms,   // [B]
    const ushort* __restrict__ Mt,     // [2048][32][32] bf16 (normalized, T)
    const int*    __restrict__ trans,  // [64]
    float*        __restrict__ out)    // [B][16384]
{
    const int bid = blockIdx.x;            // 0 .. B*4-1
    const int b   = bid >> 2;
    const int w   = threadIdx.x >> 6;      // wave 0..3
    const int l   = threadIdx.x & 63;
    const int r   = ((bid & 3) << 2) | w;  // rep 0..15

    const int esym = trans[syms[b]];
    const int lr = l & 15;                 // row (A) / col (B,C) within tile
    const int k0 = (l >> 4) << 3;          // k base {0,8,16,24}

    const float*  A  = emb + (size_t)b * EMB + (size_t)r * MATSZ;
    const ushort* Mw = Mt + ((size_t)r * NELEMS + esym) * MATSZ;

    bf16x8 af[2];
    #pragma unroll
    for (int ti = 0; ti < 2; ++ti) {
        const float* ap = A + (ti * 16 + lr) * DD + k0;
        float4 lo = *reinterpret_cast<const float4*>(ap);
        float4 hi = *reinterpret_cast<const float4*>(ap + 4);
        bf16x8 f;
        f[0] = f2bf(lo.x); f[1] = f2bf(lo.y); f[2] = f2bf(lo.z); f[3] = f2bf(lo.w);
        f[4] = f2bf(hi.x); f[5] = f2bf(hi.y); f[6] = f2bf(hi.z); f[7] = f2bf(hi.w);
        af[ti] = f;
    }

    bf16x8 bfg[2];
    #pragma unroll
    for (int tj = 0; tj < 2; ++tj)
        bfg[tj] = *reinterpret_cast<const bf16x8*>(Mw + (tj * 16 + lr) * DD + k0);

    const f32x4 z = {0.0f, 0.0f, 0.0f, 0.0f};
    f32x4 acc[2][2];
    #pragma unroll
    for (int ti = 0; ti < 2; ++ti)
        #pragma unroll
        for (int tj = 0; tj < 2; ++tj)
            acc[ti][tj] = __builtin_amdgcn_mfma_f32_16x16x32_bf16(
                af[ti], bfg[tj], z, 0, 0, 0);

    float* Ob = out + (size_t)b * EMB + (size_t)r * MATSZ;
    const int row0 = (l >> 4) << 2;        // C row base
    #pragma unroll
    for (int ti = 0; ti < 2; ++ti)
        #pragma unroll
        for (int m = 0; m < 4; ++m) {
            const int row = ti * 16 + row0 + m;
            #pragma unroll
            for (int tj = 0; tj < 2; ++tj)
                Ob[row * DD + tj * 16 + lr] = acc[ti][tj][m];
        }
}

extern "C" void kernel_launch(void* const* d_in, const int* in_sizes, int n_in,
                              void* d_out, int out_size, void* d_ws, size_t ws_size,
                              hipStream_t stream) {
    const float* emb   = (const float*)d_in[0];
    const int*   syms  = (const int*)d_in[1];
    const float* reps  = (const float*)d_in[2];
    const int*   trans = (const int*)d_in[3];
    float*  outp = (float*)d_out;
    ushort* Mt   = (ushort*)d_ws;          // 2048 * 2KB = 4 MB scratch

    const int B = in_sizes[1];             // batch count (4096)

    hipLaunchKernelGGL(prep_kernel, dim3(NREPS * NELEMS), dim3(256), 0, stream,
                       reps, Mt);
    hipLaunchKernelGGL(trans_mfma_kernel, dim3(B * 4), dim3(256), 0, stream,
                       emb, syms, Mt, trans, outp);
}